// Round 3
// baseline (473.550 us; speedup 1.0000x reference)
//
#include <hip/hip_runtime.h>

// Problem constants (fixed by setup_inputs)
#define B_   4
#define C_   256
#define H_   96
#define W_   128
#define F_   9
#define G_   4
#define CG   64            // channels per group
#define NC2  32            // channel PAIRS per group
#define NO   81            // offsets
#define TH   2             // output rows per block
#define TROWS (TH + 16)    // 18 in2 rows needed (dilation=2, r=4)
#define TCOLS (W_ + 16)    // 144 cols incl halo
#define TILE_DW (TROWS * TCOLS)  // 2592 dwords per channel-pair tile
#define NK   11            // staging chunks: ceil(2592/256)
#define HW_  (H_ * W_)

typedef _Float16 half2v __attribute__((ext_vector_type(2)));

__device__ __forceinline__ half2v u2h(unsigned u) {
    half2v h; __builtin_memcpy(&h, &u, 4); return h;
}
// cvt_pkrtz returns __fp16x2; bit-cast to our half2v (same 4 bytes)
__device__ __forceinline__ half2v pkrtz(float a, float b) {
    auto r = __builtin_amdgcn_cvt_pkrtz(a, b);
    half2v h; __builtin_memcpy(&h, &r, 4); return h;
}
__device__ __forceinline__ unsigned pkrtz_u(float a, float b) {
    auto r = __builtin_amdgcn_cvt_pkrtz(a, b);
    unsigned u; __builtin_memcpy(&u, &r, 4); return u;
}

#if __has_builtin(__builtin_amdgcn_fdot2)
#define FDOT2(a, b, c) __builtin_amdgcn_fdot2((a), (b), (c), false)
#else
__device__ __forceinline__ float fdot2_fb(half2v a, half2v b, float c) {
    return c + (float)a[0] * (float)b[0] + (float)a[1] * (float)b[1];
}
#define FDOT2(a, b, c) fdot2_fb((a), (b), (c))
#endif

// Pack weights [C,9,9] f32 -> [g][c2][o] as f16x2 (channel pair) in d_ws
__global__ void pack_weights_kernel(const float* __restrict__ w,
                                    unsigned* __restrict__ wp) {
    int i = blockIdx.x * blockDim.x + threadIdx.x;
    if (i >= G_ * NC2 * NO) return;
    int o  = i % NO;
    int c2 = (i / NO) % NC2;
    int g  = i / (NO * NC2);
    float a = w[(size_t)(g * CG + 2 * c2) * NO + o];
    float b = w[(size_t)(g * CG + 2 * c2 + 1) * NO + o];
    wp[i] = pkrtz_u(a, b);
}

template <bool PACKED>
__global__ __launch_bounds__(256)
__attribute__((amdgpu_waves_per_eu(3, 3)))   // pin 3 waves/EU -> VGPR budget ~168, no spill
void wcorr_kernel(const float* __restrict__ in1, const float* __restrict__ in2,
                  const unsigned* __restrict__ wp, const float* __restrict__ wraw,
                  float* __restrict__ out) {
    __shared__ unsigned tile[2][TILE_DW];

    // XCD-aware swizzle: pair (b,g) constant per XCD run -> in2 plane stays in XCD L2
    int bid  = blockIdx.x;          // 0..767
    int xcd  = bid & 7;
    int slot = bid >> 3;            // 0..95
    int pair = xcd + 8 * (slot / 48);  // 0..15  == b*4+g
    int hblk = slot % 48;
    int b = pair >> 2, g = pair & 3;
    int h0 = hblk * TH;

    int t  = threadIdx.x;
    int ty = t >> 7;                // 0..1
    int tx = t & 127;               // 0..127

    const float* in1g = in1 + (size_t)(b * C_ + g * CG) * HW_;
    const float* in2g = in2 + (size_t)(b * C_ + g * CG) * HW_;

    // ---- hoisted staging geometry (c2-invariant): per-k source offset or -1 ----
    int po[NK];
#pragma unroll
    for (int k = 0; k < NK; ++k) {
        int idx = k * 256 + t;
        int row = idx / TCOLS;
        int col = idx - row * TCOLS;
        int gr  = h0 - 8 + row;
        int gc  = col - 8;
        bool inb = (idx < TILE_DW) && (gr >= 0) && (gr < H_) && (gc >= 0) && (gc < W_);
        po[k] = inb ? (gr * W_ + gc) : -1;
    }

    float acc[NO];
#pragma unroll
    for (int o = 0; o < NO; ++o) acc[o] = 0.f;

    float sv0[NK], sv1[NK];   // staged in2 values (in regs while loads in flight)

    // ---- prologue: stage c2=0 ----
#pragma unroll
    for (int k = 0; k < NK; ++k) {
        sv0[k] = 0.f; sv1[k] = 0.f;
        if (po[k] >= 0) {
            const float* p = in2g + po[k];
            sv0[k] = p[0];
            sv1[k] = p[HW_];
        }
    }
#pragma unroll
    for (int k = 0; k < NK; ++k) {
        int idx = k * 256 + t;
        if (k < NK - 1 || idx < TILE_DW)
            tile[0][idx] = pkrtz_u(sv0[k], sv1[k]);
    }

    // in1 pair for c2=0
    int in1off = (h0 + ty) * W_ + tx;
    float a0 = in1g[in1off];
    float a1 = in1g[in1off + HW_];

    const int lbase = ty * TCOLS + tx;

    for (int c2 = 0; c2 < NC2; ++c2) {
        const bool more = (c2 + 1 < NC2);

        // T14: issue NEXT tile's global loads before the barrier (pure global reads)
        if (more) {
            const float* chb = in2g + (size_t)(2 * (c2 + 1)) * HW_;
#pragma unroll
            for (int k = 0; k < NK; ++k) {
                sv0[k] = 0.f; sv1[k] = 0.f;
                if (po[k] >= 0) {
                    const float* p = chb + po[k];
                    sv0[k] = p[0];
                    sv1[k] = p[HW_];
                }
            }
        }

        __syncthreads();            // tile[c2&1] fully written (end of prev iter)
        const unsigned* lt = tile[c2 & 1];

        half2v a = pkrtz(a0, a1);
        if (more) {                 // prefetch next in1 pair (used next iteration)
            const float* p = in1g + (size_t)(2 * (c2 + 1)) * HW_ + in1off;
            a0 = p[0];
            a1 = p[HW_];
        }

        const unsigned* wrow = PACKED ? (wp + ((size_t)g * NC2 + c2) * NO) : nullptr;
        const float* wr0 = wraw + (size_t)(g * CG + 2 * c2) * NO;
        const float* wr1 = wr0 + NO;

#pragma unroll
        for (int dy = 0; dy < F_; ++dy) {
#pragma unroll
            for (int dx = 0; dx < F_; ++dx) {
                const int o = dy * F_ + dx;
                unsigned uv = lt[lbase + dy * 2 * TCOLS + dx * 2]; // imm-offset ds_read
                half2v vh = u2h(uv);
                half2v wh;
                if (PACKED) {
                    wh = u2h(wrow[o]);              // wave-uniform -> s_load
                } else {
                    wh = pkrtz(wr0[o], wr1[o]);
                }
                half2v prod = wh * a;               // v_pk_mul_f16
                acc[o] = FDOT2(prod, vh, acc[o]);   // v_dot2_f32_f16
            }
        }

        // write the staged tile late (vmcnt drained only after compute issued)
        if (more) {
            unsigned* dst = tile[(c2 + 1) & 1];
#pragma unroll
            for (int k = 0; k < NK; ++k) {
                int idx = k * 256 + t;
                if (k < NK - 1 || idx < TILE_DW)
                    dst[idx] = pkrtz_u(sv0[k], sv1[k]);
            }
        }
    }

    // out[b][g*81+o][h][w]
    size_t obase = (((size_t)pair * NO) * H_ + (h0 + ty)) * W_ + tx;
#pragma unroll
    for (int o = 0; o < NO; ++o)
        out[obase + (size_t)o * HW_] = acc[o];
}

extern "C" void kernel_launch(void* const* d_in, const int* in_sizes, int n_in,
                              void* d_out, int out_size, void* d_ws, size_t ws_size,
                              hipStream_t stream) {
    const float* in1  = (const float*)d_in[0];
    const float* in2  = (const float*)d_in[1];
    const float* wraw = (const float*)d_in[2];
    float* out = (float*)d_out;

    const size_t wp_bytes = (size_t)G_ * NC2 * NO * 4;  // 41,472 B
    const int nblocks = B_ * G_ * (H_ / TH);            // 768 = 3 per CU

    if (ws_size >= wp_bytes) {
        unsigned* wp = (unsigned*)d_ws;
        int n = G_ * NC2 * NO;
        pack_weights_kernel<<<(n + 255) / 256, 256, 0, stream>>>(wraw, wp);
        wcorr_kernel<true><<<nblocks, 256, 0, stream>>>(in1, in2, wp, wraw, out);
    } else {
        wcorr_kernel<false><<<nblocks, 256, 0, stream>>>(in1, in2, nullptr, wraw, out);
    }
}

// Round 4
// 107.360 us; speedup vs baseline: 4.4109x; 4.4109x over previous
//
#include <hip/hip_runtime.h>

// Problem constants (fixed by setup_inputs)
#define B_   4
#define C_   256
#define H_   96
#define W_   128
#define F_   9
#define G_   4
#define CG   64            // channels per group
#define NC2  32            // channel PAIRS per group
#define NO   81            // offsets
#define TH   2             // output rows per block
#define TCOLS (W_ + 16)    // 144 cols incl halo
#define HW_  (H_ * W_)

// Per-pass geometry: NDY dy-values per pass; dilation=2 => rows needed are
// h0-8+2*DY0 .. h0-8+2*DY0+2*NDY-1 (TH=2 fills in the odd rows)
#define NDY   3
#define PROWS (2 * NDY)          // 6 tile rows per pass
#define PTDW  (PROWS * TCOLS)    // 864 dwords per channel-pair tile
#define PNK   4                  // ceil(864/256)

typedef _Float16 half2v __attribute__((ext_vector_type(2)));

__device__ __forceinline__ half2v u2h(unsigned u) {
    half2v h; __builtin_memcpy(&h, &u, 4); return h;
}
__device__ __forceinline__ half2v pkrtz(float a, float b) {
    auto r = __builtin_amdgcn_cvt_pkrtz(a, b);
    half2v h; __builtin_memcpy(&h, &r, 4); return h;
}
__device__ __forceinline__ unsigned pkrtz_u(float a, float b) {
    auto r = __builtin_amdgcn_cvt_pkrtz(a, b);
    unsigned u; __builtin_memcpy(&u, &r, 4); return u;
}

#if __has_builtin(__builtin_amdgcn_fdot2)
#define FDOT2(a, b, c) __builtin_amdgcn_fdot2((a), (b), (c), false)
#else
__device__ __forceinline__ float fdot2_fb(half2v a, half2v b, float c) {
    return c + (float)a[0] * (float)b[0] + (float)a[1] * (float)b[1];
}
#define FDOT2(a, b, c) fdot2_fb((a), (b), (c))
#endif

// Pack weights [C,9,9] f32 -> [g][c2][o] as f16x2 (channel pair) in d_ws
__global__ void pack_weights_kernel(const float* __restrict__ w,
                                    unsigned* __restrict__ wp) {
    int i = blockIdx.x * blockDim.x + threadIdx.x;
    if (i >= G_ * NC2 * NO) return;
    int o  = i % NO;
    int c2 = (i / NO) % NC2;
    int g  = i / (NO * NC2);
    float a = w[(size_t)(g * CG + 2 * c2) * NO + o];
    float b = w[(size_t)(g * CG + 2 * c2 + 1) * NO + o];
    wp[i] = pkrtz_u(a, b);
}

// One dy-pass: 27 offsets, full channel loop, 27 f32 accumulators
template <int DY0, bool PACKED>
__device__ __forceinline__ void do_pass(
    const float* __restrict__ in1g, const float* __restrict__ in2g,
    const unsigned* __restrict__ wp, const float* __restrict__ wraw,
    float* __restrict__ out, unsigned (*tile)[PTDW],
    int g, int h0, int t, int ty, int tx, size_t obase)
{
    // staging geometry for this pass (c2-invariant)
    int po[PNK];
#pragma unroll
    for (int k = 0; k < PNK; ++k) {
        int idx = k * 256 + t;
        int row = idx / TCOLS;
        int col = idx - row * TCOLS;
        int gr  = h0 - 8 + 2 * DY0 + row;
        int gc  = col - 8;
        bool inb = (idx < PTDW) && (gr >= 0) && (gr < H_) && (gc >= 0) && (gc < W_);
        po[k] = inb ? (gr * W_ + gc) : -1;
    }

    float acc[NDY * F_];
#pragma unroll
    for (int o = 0; o < NDY * F_; ++o) acc[o] = 0.f;

    // prologue: stage c2=0 into tile[0]
#pragma unroll
    for (int k = 0; k < PNK; ++k) {
        int idx = k * 256 + t;
        float v0 = 0.f, v1 = 0.f;
        if (po[k] >= 0) { v0 = in2g[po[k]]; v1 = in2g[po[k] + HW_]; }
        if (idx < PTDW) tile[0][idx] = pkrtz_u(v0, v1);
    }

    const int in1off = (h0 + ty) * W_ + tx;
    float a0 = in1g[in1off], a1 = in1g[in1off + HW_];

    const int lbase = ty * TCOLS + tx;

    for (int c2 = 0; c2 < NC2; ++c2) {
        const bool more = (c2 + 1 < NC2);

        // issue next tile's global loads BEFORE the barrier (in flight across it)
        float v0[PNK], v1[PNK];
        if (more) {
            const float* chb = in2g + (size_t)(2 * (c2 + 1)) * HW_;
#pragma unroll
            for (int k = 0; k < PNK; ++k) {
                v0[k] = 0.f; v1[k] = 0.f;
                if (po[k] >= 0) { v0[k] = chb[po[k]]; v1[k] = chb[po[k] + HW_]; }
            }
        }

        __syncthreads();   // tile[c2&1] ready; everyone done reading tile[(c2+1)&1]

        if (more) {
            unsigned* dst = tile[(c2 + 1) & 1];
#pragma unroll
            for (int k = 0; k < PNK; ++k) {
                int idx = k * 256 + t;
                if (idx < PTDW) dst[idx] = pkrtz_u(v0[k], v1[k]);
            }
        }

        const unsigned* lt = tile[c2 & 1];
        half2v a = pkrtz(a0, a1);
        if (more) {   // prefetch next in1 pair
            const float* p = in1g + (size_t)(2 * (c2 + 1)) * HW_ + in1off;
            a0 = p[0]; a1 = p[HW_];
        }

        const unsigned* wrow = PACKED ? (wp + ((size_t)g * NC2 + c2) * NO + DY0 * F_) : nullptr;
        const float* wr0 = wraw + (size_t)(g * CG + 2 * c2) * NO + DY0 * F_;
        const float* wr1 = wr0 + NO;

#pragma unroll
        for (int dyp = 0; dyp < NDY; ++dyp) {
#pragma unroll
            for (int dx = 0; dx < F_; ++dx) {
                const int oo = dyp * F_ + dx;
                unsigned uv = lt[lbase + dyp * 2 * TCOLS + dx * 2]; // imm-offset ds_read
                half2v vh = u2h(uv);
                half2v wh = PACKED ? u2h(wrow[oo]) : pkrtz(wr0[oo], wr1[oo]);
                half2v prod = wh * a;               // v_pk_mul_f16
                acc[oo] = FDOT2(prod, vh, acc[oo]); // v_dot2_f32_f16
            }
        }
    }

    // write this pass's 27 output planes
#pragma unroll
    for (int oo = 0; oo < NDY * F_; ++oo)
        out[obase + (size_t)(DY0 * F_ + oo) * HW_] = acc[oo];
}

template <bool PACKED>
__global__ __launch_bounds__(256)
void wcorr_kernel(const float* __restrict__ in1, const float* __restrict__ in2,
                  const unsigned* __restrict__ wp, const float* __restrict__ wraw,
                  float* __restrict__ out) {
    __shared__ unsigned tile[2][PTDW];

    // XCD-aware swizzle: pair (b,g) constant per XCD run -> in2 plane stays in XCD L2
    int bid  = blockIdx.x;          // 0..767
    int xcd  = bid & 7;
    int slot = bid >> 3;            // 0..95
    int pair = xcd + 8 * (slot / 48);  // 0..15  == b*4+g
    int hblk = slot % 48;
    int b = pair >> 2, g = pair & 3;
    int h0 = hblk * TH;

    int t  = threadIdx.x;
    int ty = t >> 7;                // 0..1
    int tx = t & 127;               // 0..127

    const float* in1g = in1 + (size_t)(b * C_ + g * CG) * HW_;
    const float* in2g = in2 + (size_t)(b * C_ + g * CG) * HW_;

    size_t obase = (((size_t)pair * NO) * H_ + (h0 + ty)) * W_ + tx;

    do_pass<0, PACKED>(in1g, in2g, wp, wraw, out, tile, g, h0, t, ty, tx, obase);
    __syncthreads();
    do_pass<3, PACKED>(in1g, in2g, wp, wraw, out, tile, g, h0, t, ty, tx, obase);
    __syncthreads();
    do_pass<6, PACKED>(in1g, in2g, wp, wraw, out, tile, g, h0, t, ty, tx, obase);
}

extern "C" void kernel_launch(void* const* d_in, const int* in_sizes, int n_in,
                              void* d_out, int out_size, void* d_ws, size_t ws_size,
                              hipStream_t stream) {
    const float* in1  = (const float*)d_in[0];
    const float* in2  = (const float*)d_in[1];
    const float* wraw = (const float*)d_in[2];
    float* out = (float*)d_out;

    const size_t wp_bytes = (size_t)G_ * NC2 * NO * 4;  // 41,472 B
    const int nblocks = B_ * G_ * (H_ / TH);            // 768 = 3 per CU

    if (ws_size >= wp_bytes) {
        unsigned* wp = (unsigned*)d_ws;
        int n = G_ * NC2 * NO;
        pack_weights_kernel<<<(n + 255) / 256, 256, 0, stream>>>(wraw, wp);
        wcorr_kernel<true><<<nblocks, 256, 0, stream>>>(in1, in2, wp, wraw, out);
    } else {
        wcorr_kernel<false><<<nblocks, 256, 0, stream>>>(in1, in2, nullptr, wraw, out);
    }
}

// Round 5
// 78.902 us; speedup vs baseline: 6.0017x; 1.3607x over previous
//
#include <hip/hip_runtime.h>

// Problem constants (fixed by setup_inputs)
#define B_   4
#define C_   256
#define H_   96
#define W_   128
#define F_   9
#define G_   4
#define CG   64            // channels per group
#define NC4  16            // channel QUADS per group
#define NO   81            // offsets
#define TH   2             // output rows per block
#define TCOLS (W_ + 16)    // 144 cols incl halo
#define HW_  (H_ * W_)

// Per-pass geometry: 3 dy-values per pass (dy = pass*3 + dyp)
#define NDY   3
#define PROWS (2 * NDY)          // 6 tile rows per pass (dilation=2, TH=2)
#define PTE   (PROWS * TCOLS)    // 864 tile elements (8B each: 4 channels f16)
#define PNK   4                  // ceil(864/256) staging chunks

typedef _Float16 half2v __attribute__((ext_vector_type(2)));
typedef unsigned u32x2 __attribute__((ext_vector_type(2)));

__device__ __forceinline__ half2v u2h(unsigned u) {
    half2v h; __builtin_memcpy(&h, &u, 4); return h;
}
__device__ __forceinline__ half2v pkrtz(float a, float b) {
    auto r = __builtin_amdgcn_cvt_pkrtz(a, b);
    half2v h; __builtin_memcpy(&h, &r, 4); return h;
}
__device__ __forceinline__ unsigned pkrtz_u(float a, float b) {
    auto r = __builtin_amdgcn_cvt_pkrtz(a, b);
    unsigned u; __builtin_memcpy(&u, &r, 4); return u;
}

#if __has_builtin(__builtin_amdgcn_fdot2)
#define FDOT2(a, b, c) __builtin_amdgcn_fdot2((a), (b), (c), false)
#else
__device__ __forceinline__ float fdot2_fb(half2v a, half2v b, float c) {
    return c + (float)a[0] * (float)b[0] + (float)a[1] * (float)b[1];
}
#define FDOT2(a, b, c) fdot2_fb((a), (b), (c))
#endif

// Pack weights [C,9,9] f32 -> [g][c4][o] as 4-channel (2x f16x2) in d_ws
__global__ void pack_weights_kernel(const float* __restrict__ w,
                                    u32x2* __restrict__ wp) {
    int i = blockIdx.x * blockDim.x + threadIdx.x;
    if (i >= G_ * NC4 * NO) return;
    int o  = i % NO;
    int c4 = (i / NO) % NC4;
    int g  = i / (NO * NC4);
    const float* base = w + (size_t)(g * CG + 4 * c4) * NO + o;
    u32x2 r;
    r.x = pkrtz_u(base[0], base[NO]);
    r.y = pkrtz_u(base[2 * NO], base[3 * NO]);
    wp[i] = r;
}

template <bool PACKED>
__global__ __launch_bounds__(256)
void wcorr_kernel(const float* __restrict__ in1, const float* __restrict__ in2,
                  const u32x2* __restrict__ wp, const float* __restrict__ wraw,
                  float* __restrict__ out) {
    __shared__ u32x2 tile[2][PTE];   // 13,824 B

    // grid = 16 pairs x 3 passes x 48 hblks = 2304 blocks
    // XCD-aware: pair constant per XCD run -> in2 plane stays in XCD L2
    int bid  = blockIdx.x;
    int xcd  = bid & 7;
    int slot = bid >> 3;                 // 0..287
    int pair = xcd + 8 * (slot / 144);   // 0..15  == b*4+g
    int rem  = slot % 144;
    int pass = rem / 48;                 // 0..2  (dy block)
    int hblk = rem % 48;
    int b = pair >> 2, g = pair & 3;
    int h0 = hblk * TH;

    int t  = threadIdx.x;
    int ty = t >> 7;                // 0..1
    int tx = t & 127;               // 0..127

    const float* in1g = in1 + (size_t)(b * C_ + g * CG) * HW_;
    const float* in2g = in2 + (size_t)(b * C_ + g * CG) * HW_;

    // staging geometry (channel-invariant): tile rows cover gr0..gr0+5
    const int gr0 = h0 - 8 + 6 * pass;
    int po[PNK];
#pragma unroll
    for (int k = 0; k < PNK; ++k) {
        int idx = k * 256 + t;
        int row = idx / TCOLS;
        int col = idx - row * TCOLS;
        int gr  = gr0 + row;
        int gc  = col - 8;
        bool inb = (idx < PTE) && (gr >= 0) && (gr < H_) && (gc >= 0) && (gc < W_);
        po[k] = inb ? (gr * W_ + gc) : -1;
    }

    float acc[NDY * F_];
#pragma unroll
    for (int o = 0; o < NDY * F_; ++o) acc[o] = 0.f;

    // prologue: stage c4=0 into tile[0]
#pragma unroll
    for (int k = 0; k < PNK; ++k) {
        int idx = k * 256 + t;
        float v0 = 0.f, v1 = 0.f, v2 = 0.f, v3 = 0.f;
        if (po[k] >= 0) {
            const float* p = in2g + po[k];
            v0 = p[0]; v1 = p[HW_]; v2 = p[2 * HW_]; v3 = p[3 * HW_];
        }
        if (idx < PTE) {
            u32x2 r; r.x = pkrtz_u(v0, v1); r.y = pkrtz_u(v2, v3);
            tile[0][idx] = r;
        }
    }

    const int in1off = (h0 + ty) * W_ + tx;
    float a0 = in1g[in1off], a1 = in1g[in1off + HW_];
    float a2 = in1g[in1off + 2 * HW_], a3 = in1g[in1off + 3 * HW_];

    const int lbase = ty * TCOLS + tx;

    for (int c4 = 0; c4 < NC4; ++c4) {
        const bool more = (c4 + 1 < NC4);

        // issue next tile's global loads BEFORE the barrier (in flight across it)
        float v0[PNK], v1[PNK], v2[PNK], v3[PNK];
        if (more) {
            const float* chb = in2g + (size_t)(4 * (c4 + 1)) * HW_;
#pragma unroll
            for (int k = 0; k < PNK; ++k) {
                v0[k] = 0.f; v1[k] = 0.f; v2[k] = 0.f; v3[k] = 0.f;
                if (po[k] >= 0) {
                    const float* p = chb + po[k];
                    v0[k] = p[0]; v1[k] = p[HW_];
                    v2[k] = p[2 * HW_]; v3[k] = p[3 * HW_];
                }
            }
        }

        __syncthreads();   // tile[c4&1] ready; all readers done with tile[(c4+1)&1]

        if (more) {
            u32x2* dst = tile[(c4 + 1) & 1];
#pragma unroll
            for (int k = 0; k < PNK; ++k) {
                int idx = k * 256 + t;
                if (idx < PTE) {
                    u32x2 r; r.x = pkrtz_u(v0[k], v1[k]); r.y = pkrtz_u(v2[k], v3[k]);
                    dst[idx] = r;
                }
            }
        }

        const u32x2* lt = tile[c4 & 1];
        half2v ha = pkrtz(a0, a1);
        half2v hb = pkrtz(a2, a3);
        if (more) {   // prefetch next in1 quad
            const float* p = in1g + (size_t)(4 * (c4 + 1)) * HW_ + in1off;
            a0 = p[0]; a1 = p[HW_]; a2 = p[2 * HW_]; a3 = p[3 * HW_];
        }

        const u32x2* wrow = PACKED ? (wp + ((size_t)g * NC4 + c4) * NO + pass * NDY * F_) : nullptr;
        const float* wr = wraw + (size_t)(g * CG + 4 * c4) * NO + pass * NDY * F_;

#pragma unroll
        for (int dyp = 0; dyp < NDY; ++dyp) {
#pragma unroll
            for (int dx = 0; dx < F_; ++dx) {
                const int oo = dyp * F_ + dx;
                u32x2 uv = lt[lbase + dyp * 2 * TCOLS + dx * 2]; // ds_read_b64, imm offset
                half2v wa, wb;
                if (PACKED) {
                    u32x2 wv = wrow[oo];            // wave-uniform -> s_load
                    wa = u2h(wv.x); wb = u2h(wv.y);
                } else {
                    wa = pkrtz(wr[oo], wr[oo + NO]);
                    wb = pkrtz(wr[oo + 2 * NO], wr[oo + 3 * NO]);
                }
                half2v p0 = wa * ha;                // v_pk_mul_f16
                half2v p1 = wb * hb;
                float s = FDOT2(p0, u2h(uv.x), acc[oo]);
                acc[oo]  = FDOT2(p1, u2h(uv.y), s); // v_dot2_f32_f16 x2
            }
        }
    }

    // write this pass's 27 output planes: out[b][g*81 + pass*27 + oo][h][w]
    size_t obase = (((size_t)pair * NO + pass * NDY * F_) * H_ + (h0 + ty)) * W_ + tx;
#pragma unroll
    for (int oo = 0; oo < NDY * F_; ++oo)
        out[obase + (size_t)oo * HW_] = acc[oo];
}

extern "C" void kernel_launch(void* const* d_in, const int* in_sizes, int n_in,
                              void* d_out, int out_size, void* d_ws, size_t ws_size,
                              hipStream_t stream) {
    const float* in1  = (const float*)d_in[0];
    const float* in2  = (const float*)d_in[1];
    const float* wraw = (const float*)d_in[2];
    float* out = (float*)d_out;

    const size_t wp_bytes = (size_t)G_ * NC4 * NO * 8;  // 41,472 B
    const int nblocks = 16 * 3 * (H_ / TH);             // 2304

    if (ws_size >= wp_bytes) {
        u32x2* wp = (u32x2*)d_ws;
        int n = G_ * NC4 * NO;
        pack_weights_kernel<<<(n + 255) / 256, 256, 0, stream>>>(wraw, wp);
        wcorr_kernel<true><<<nblocks, 256, 0, stream>>>(in1, in2, wp, wraw, out);
    } else {
        wcorr_kernel<false><<<nblocks, 256, 0, stream>>>(in1, in2, nullptr, wraw, out);
    }
}